// Round 2
// baseline (2701.142 us; speedup 1.0000x reference)
//
#include <hip/hip_runtime.h>
#include <hip/hip_bf16.h>

// Experts MoE FFN: out = gelu(x@W1 + b1) @ W2 + b2, per-expert contiguous token chunks.
// T=16384 E=8 D=2048 F=8192, fp32 in/out; internally bf16 MFMA with fp32 accum.
//
// ws layout (537 MB total):
//   Wt  bf16 [268.4 MB]  -- holds W1t [E][F][D] for GEMM1, then W2t [E][D][F] for GEMM2
//   h   bf16 [T][F] [268.4 MB]
// x_bf16 [T][D] (67 MB) is staged in d_out (134 MB fp32 region); dead before GEMM2 writes out.

#define T_TOK 16384
#define E_EXP 8
#define D_MOD 2048
#define F_FF  8192

typedef __attribute__((ext_vector_type(8))) __bf16 bf16x8;
typedef __attribute__((ext_vector_type(4))) float f32x4;
typedef __attribute__((ext_vector_type(8))) unsigned short u16x8;

__device__ __forceinline__ unsigned short f2bf(float f) {
  unsigned u = __builtin_bit_cast(unsigned, f);
  u += 0x7fffu + ((u >> 16) & 1u);
  return (unsigned short)(u >> 16);
}

// ---------------- x fp32 -> bf16 (one thread per 8 elems) ----------------
__global__ __launch_bounds__(256) void cvt_bf16_kernel(const float* __restrict__ in,
                                                       unsigned short* __restrict__ out) {
  size_t i = (size_t)blockIdx.x * 256 + threadIdx.x;
  const float4* p = (const float4*)in + i * 2;
  float4 a = p[0], b = p[1];
  u16x8 o;
  o[0] = f2bf(a.x); o[1] = f2bf(a.y); o[2] = f2bf(a.z); o[3] = f2bf(a.w);
  o[4] = f2bf(b.x); o[5] = f2bf(b.y); o[6] = f2bf(b.z); o[7] = f2bf(b.w);
  ((u16x8*)out)[i] = o;
}

// ---------------- W [E][R][C] fp32 -> Wt [E][C][R] bf16 (64x64 LDS tile transpose) ----
__global__ __launch_bounds__(256) void cvt_t_kernel(const float* __restrict__ W,
                                                    unsigned short* __restrict__ Wt,
                                                    int R, int C, int rtiles, int ctiles) {
  __shared__ unsigned short tile[64][80];  // [c][r], stride 160B (16B aligned)
  int bid = blockIdx.x;
  int per_e = rtiles * ctiles;
  int e = bid / per_e;
  int rr = bid - e * per_e;
  int rt = rr / ctiles;
  int ct = rr - rt * ctiles;
  int t = threadIdx.x;
  int row = t >> 2;           // 0..63 (r within tile)
  int cb = (t & 3) * 16;      // c base within tile
  const float* src = W + ((size_t)e * R + (size_t)rt * 64) * C + (size_t)ct * 64;
  const float4* sp = (const float4*)(src + (size_t)row * C + cb);
  float4 v0 = sp[0], v1 = sp[1], v2 = sp[2], v3 = sp[3];
  float vv[16] = {v0.x, v0.y, v0.z, v0.w, v1.x, v1.y, v1.z, v1.w,
                  v2.x, v2.y, v2.z, v2.w, v3.x, v3.y, v3.z, v3.w};
#pragma unroll
  for (int j = 0; j < 16; j++) tile[cb + j][row] = f2bf(vv[j]);
  __syncthreads();
  // thread t writes c-row = row, r-cols [cb, cb+16)
  unsigned short* dst = Wt + ((size_t)e * C + (size_t)ct * 64 + row) * R + (size_t)rt * 64 + cb;
  const u16x8* tp = (const u16x8*)&tile[row][cb];
  ((u16x8*)dst)[0] = tp[0];
  ((u16x8*)dst)[1] = tp[1];
}

// ---------------- grouped GEMM: C[e] = A[e] (MxK) * Bt[e] (NxK)^T + bias ----------------
// m97 structure: 128x128 tile, BK=32, 4 waves (2x2), 4x4 frags of 16x16x32, global_load_lds.
#define BM 128
#define BN 128
#define BK 32

__device__ __forceinline__ void gload16(const unsigned short* g, unsigned short* l) {
  __builtin_amdgcn_global_load_lds(
      (const __attribute__((address_space(1))) unsigned int*)g,
      (__attribute__((address_space(3))) unsigned int*)l, 16, 0, 0);
}

template <int EPI>  // 0: bias+gelu -> bf16 ; 1: bias -> fp32
__global__ __launch_bounds__(256, 2) void gemm_bias_kernel(
    const unsigned short* __restrict__ A,   // [E*Mper][K] bf16
    const unsigned short* __restrict__ Bt,  // [E][N][K] bf16
    const float* __restrict__ bias,         // [E][N]
    void* __restrict__ C,                   // [E*Mper][N] bf16 (EPI=0) / fp32 (EPI=1)
    int Mper, int N, int K, int mtiles, int ntiles) {
  __shared__ __align__(16) unsigned short lA[BM * BK];  // 8KB
  __shared__ __align__(16) unsigned short lB[BN * BK];  // 8KB

  // XCD-chunked swizzle (nwg % 8 == 0): each XCD gets a contiguous logical chunk.
  int nwg = gridDim.x;
  int cpx = nwg >> 3;
  int bid = blockIdx.x;
  int wgid = (bid & 7) * cpx + (bid >> 3);

  int bpe = mtiles * ntiles;
  int e = wgid / bpe;
  int r = wgid - e * bpe;
  int mt = r / ntiles;       // consecutive wgid: same mt (A panel L2-resident), nt varies
  int nt = r - mt * ntiles;

  const int tid = threadIdx.x;
  const int w = tid >> 6;
  const int lane = tid & 63;
  const int wm = w >> 1, wn = w & 1;

  const unsigned short* Ab = A + (size_t)(e * Mper + mt * BM) * K;
  const unsigned short* Bb = Bt + ((size_t)e * N + (size_t)nt * BN) * K;

  // staging: 512 chunks of 16B per tile; thread covers chunks c0=w*64+lane and c0+256
  int c0 = w * 64 + lane;
  int c1 = c0 + 256;
  size_t ga0 = (size_t)(c0 >> 2) * K + (c0 & 3) * 8;
  size_t ga1 = (size_t)(c1 >> 2) * K + (c1 & 3) * 8;

  f32x4 acc[4][4];
#pragma unroll
  for (int i = 0; i < 4; i++)
#pragma unroll
    for (int j = 0; j < 4; j++) acc[i][j] = (f32x4){0.f, 0.f, 0.f, 0.f};

  const int rbase = wm * 64 + (lane & 15);
  const int nbase = wn * 64 + (lane & 15);
  const int kpart = (lane >> 4) * 8;

  for (int k0 = 0; k0 < K; k0 += BK) {
    __syncthreads();  // previous compute done before overwriting LDS
    gload16(Ab + k0 + ga0, lA + w * 512);
    gload16(Ab + k0 + ga1, lA + 2048 + w * 512);
    gload16(Bb + k0 + ga0, lB + w * 512);
    gload16(Bb + k0 + ga1, lB + 2048 + w * 512);
    asm volatile("s_waitcnt vmcnt(0)" ::: "memory");
    __syncthreads();

    bf16x8 af[4], bfr[4];
#pragma unroll
    for (int i = 0; i < 4; i++)
      af[i] = *(const bf16x8*)&lA[(rbase + i * 16) * BK + kpart];
#pragma unroll
    for (int j = 0; j < 4; j++)
      bfr[j] = *(const bf16x8*)&lB[(nbase + j * 16) * BK + kpart];
#pragma unroll
    for (int i = 0; i < 4; i++)
#pragma unroll
      for (int j = 0; j < 4; j++)
        acc[i][j] = __builtin_amdgcn_mfma_f32_16x16x32_bf16(af[i], bfr[j], acc[i][j], 0, 0, 0);
  }

  // epilogue: C/D layout col = lane&15, row = (lane>>4)*4 + q  [verified m89/m91]
  int gmBase = e * Mper + mt * BM + wm * 64;
  int gnBase = nt * BN + wn * 64;
#pragma unroll
  for (int i = 0; i < 4; i++) {
#pragma unroll
    for (int j = 0; j < 4; j++) {
      int col = gnBase + j * 16 + (lane & 15);
      float bv = bias[(size_t)e * N + col];
      int row0 = gmBase + i * 16 + (lane >> 4) * 4;
#pragma unroll
      for (int q = 0; q < 4; q++) {
        float v = acc[i][j][q] + bv;
        size_t off = (size_t)(row0 + q) * N + col;
        if (EPI == 0) {
          // gelu tanh-approx (jax.nn.gelu default), sigmoid form (tail-stable):
          // gelu(v) = v / (1 + exp(-2*0.7978845608*(v + 0.044715 v^3)))
          float z2 = 1.5957691216057308f * (v + 0.044715f * v * v * v);
          float g = v / (1.0f + __expf(-z2));
          ((unsigned short*)C)[off] = f2bf(g);
        } else {
          ((float*)C)[off] = v;
        }
      }
    }
  }
}

extern "C" void kernel_launch(void* const* d_in, const int* in_sizes, int n_in,
                              void* d_out, int out_size, void* d_ws, size_t ws_size,
                              hipStream_t stream) {
  const float* x = (const float*)d_in[0];
  const float* W1 = (const float*)d_in[1];
  const float* b1 = (const float*)d_in[2];
  const float* W2 = (const float*)d_in[3];
  const float* b2 = (const float*)d_in[4];
  float* out = (float*)d_out;

  unsigned short* Wt = (unsigned short*)d_ws;                  // 268.4 MB, reused W1t -> W2t
  unsigned short* h = Wt + (size_t)E_EXP * F_FF * D_MOD;       // [T][F] bf16, 268.4 MB
  unsigned short* xb = (unsigned short*)d_out;                 // [T][D] bf16 staged in d_out

  // 1) x -> bf16 (into d_out; dead before GEMM2 overwrites d_out)
  cvt_bf16_kernel<<<(T_TOK * (size_t)D_MOD / 8 + 255) / 256, 256, 0, stream>>>(x, xb);
  // 2) W1 [E][D][F] -> Wt = W1t [E][F][D] bf16
  cvt_t_kernel<<<E_EXP * (D_MOD / 64) * (F_FF / 64), 256, 0, stream>>>(W1, Wt, D_MOD, F_FF,
                                                                      D_MOD / 64, F_FF / 64);
  // 3) GEMM1: h = gelu(x @ W1 + b1)   M=2048/expert, N=8192, K=2048
  gemm_bias_kernel<0><<<E_EXP * (2048 / BM) * (F_FF / BN), 256, 0, stream>>>(
      xb, Wt, b1, h, 2048, F_FF, D_MOD, 2048 / BM, F_FF / BN);
  // 4) W2 [E][F][D] -> Wt = W2t [E][D][F] bf16 (W1t dead)
  cvt_t_kernel<<<E_EXP * (F_FF / 64) * (D_MOD / 64), 256, 0, stream>>>(W2, Wt, F_FF, D_MOD,
                                                                      F_FF / 64, D_MOD / 64);
  // 5) GEMM2: out = h @ W2 + b2       M=2048/expert, N=2048, K=8192
  gemm_bias_kernel<1><<<E_EXP * (2048 / BM) * (D_MOD / BN), 256, 0, stream>>>(
      h, Wt, b2, out, 2048, D_MOD, F_FF, 2048 / BM, D_MOD / BN);
}